// Round 14
// baseline (56.426 us; speedup 1.0000x reference)
//
#include <hip/hip_runtime.h>

// GraphConv: out = d ∘ (A @ ((d∘X) @ W^T)) + b,  d = rsqrt(clip(rowsum(A),1e-6))
// B=4, N=2048, F=128. All f32 I/O, size-based binding (R6-verified).
// R13 post-mortem: Abf16 staging rejected (k3 not fetch-bound). R14: k3
// restructured to tile 32n x 64o, BK=128 -> 16 iterations (was 32), 8 MFMA
// per wave per barrier (was 4), ~195 MB cache traffic (was 290). Depth-2
// register prefetch, named sets, double-buffered LDS. Same k-order =>
// absmax bit-identical (0.00390625). k1/k2 = R12 verbatim.

#define NN 2048
#define FF 128
#define WS_NEED (32768u + 4u * 128u * 2048u * 2u)   // dinv(32KB)+Zt(2MB)

typedef __attribute__((ext_vector_type(4))) float f32x4;
typedef __attribute__((ext_vector_type(8))) short short8;

// f32 -> bf16 round-to-nearest-even (finite inputs only)
__device__ inline unsigned short f2bf(float f) {
    unsigned u = __builtin_bit_cast(unsigned, f);
    u = (u + 0x7fffu + ((u >> 16) & 1u)) >> 16;
    return (unsigned short)u;
}

__device__ inline short8 cvt8(f32x4 a, f32x4 b) {
    short8 r;
    r[0] = (short)f2bf(a.x); r[1] = (short)f2bf(a.y);
    r[2] = (short)f2bf(a.z); r[3] = (short)f2bf(a.w);
    r[4] = (short)f2bf(b.x); r[5] = (short)f2bf(b.y);
    r[6] = (short)f2bf(b.z); r[7] = (short)f2bf(b.w);
    return r;
}

// ---- k1: dinv[row] = rsqrt(max(rowsum(A),1e-6))  [R12 verbatim] ------------
__global__ __launch_bounds__(256) void k1_deg(const float* __restrict__ A,
                                              float* __restrict__ dinv) {
    __shared__ float red[256];
    int row = blockIdx.x;
    int t = threadIdx.x;
    const f32x4* ap = (const f32x4*)(A + (size_t)row * NN);
    f32x4 v0 = ap[t];
    f32x4 v1 = ap[t + 256];
    red[t] = v0.x + v0.y + v0.z + v0.w + v1.x + v1.y + v1.z + v1.w;
    __syncthreads();
    #pragma unroll
    for (int s = 128; s > 0; s >>= 1) {
        if (t < s) red[t] += red[t + s];
        __syncthreads();
    }
    if (t == 0) dinv[row] = rsqrtf(fmaxf(red[0], 1e-6f));
}

// ---- k2: Zt[b][o][m] = bf16(dinv[b,m] * dot(X[b,m,:], W[o,:]))  [R12 verbatim]
__global__ __launch_bounds__(256) void k2_zt(const float* __restrict__ X,
                                             const float* __restrict__ W,
                                             const float* __restrict__ dinv,
                                             unsigned short* __restrict__ Zt) {
    __shared__ float Ws[FF * FF];           // 64 KB
    int blk = blockIdx.x;
    int b  = blk >> 6;                      // 0..3
    int mc = (blk >> 3) & 7;                // 0..7
    int oc = blk & 7;                       // 0..7
    int t  = threadIdx.x;
    int m  = mc * 256 + t;                  // 0..2047

    {
        f32x4* wd = (f32x4*)Ws;
        const f32x4* wsrc = (const f32x4*)W;
        #pragma unroll
        for (int j = 0; j < 16; ++j) wd[t + 256 * j] = wsrc[t + 256 * j];
    }
    __syncthreads();

    float acc[16];
    #pragma unroll
    for (int j = 0; j < 16; ++j) acc[j] = 0.f;

    const f32x4* xr = (const f32x4*)(X + ((size_t)b * NN + m) * FF);
    for (int f4 = 0; f4 < FF / 4; ++f4) {
        f32x4 xv = xr[f4];
        #pragma unroll
        for (int j = 0; j < 16; ++j) {
            f32x4 wv = *(const f32x4*)&Ws[(oc * 16 + j) * FF + f4 * 4];
            acc[j] += xv.x * wv.x + xv.y * wv.y + xv.z * wv.z + xv.w * wv.w;
        }
    }
    float dv = dinv[b * NN + m];
    #pragma unroll
    for (int j = 0; j < 16; ++j)
        Zt[((size_t)b * FF + oc * 16 + j) * NN + m] = f2bf(acc[j] * dv);
}

// ---- k3: out[b,n,o] = dinv[b,n] * sum_m A[b,n,m]*Z[m,o] + bias[o] ----------
// 512 blocks = b(4) x ntile(64: 32 rows) x ohalf(2: 64 cols). 4 waves in a
// 2x2 grid: wave w owns (16n x 32o) quadrant (wr=(w>>1)*16, wc=(w&1)*32).
// BK=128, 16 iterations; double-buffered LDS (51 KB); depth-2 register
// prefetch with named sets P/Q. Rows padded to 136 shorts (272 B -> 4-bank
// row step, 2-way aliasing = free). Fragment conventions identical to
// R10..R13 (verified). Same k-accumulation order => bit-identical output.
__global__ __launch_bounds__(256) void k3_mfma(const float* __restrict__ A,
                                               const unsigned short* __restrict__ Zt,
                                               const float* __restrict__ dinv,
                                               const float* __restrict__ bias,
                                               float* __restrict__ out) {
    __shared__ unsigned short As[2][32][136];   // A tile  [n][k] bf16 (17.4 KB)
    __shared__ unsigned short Zs[2][64][136];   // Z^T tile [o][k] bf16 (34.8 KB)
    int blk = blockIdx.x;                   // 0..511
    int b   = blk >> 7;                     // 0..3
    int rem = blk & 127;
    int n0  = (rem >> 1) * 32;              // 0..2016
    int o0  = (rem & 1) * 64;               // 0 or 64
    int t   = threadIdx.x;
    int w   = t >> 6, lane = t & 63;
    int wr  = (w >> 1) * 16;                // wave row offset
    int wc  = (w & 1) * 32;                 // wave col offset
    int l15 = lane & 15, kgrp = (lane >> 4) * 8;

    const float* Ab = A + (size_t)b * NN * NN;
    const unsigned short* Zb = Zt + (size_t)b * FF * NN;

    // staging assignments (BK=128 chunk)
    int ar = t >> 3;                        // 0..31 (A row)
    int ac = (t & 7) * 16;                  // 0..112 (A col, 16 bf16/thread)
    int zo = t >> 2;                        // 0..63 (Zt row)
    int zc = (t & 3) * 32;                  // 0..96 (Zt col, 32 bf16/thread)

    f32x4 acc[2];
    acc[0] = (f32x4){0.f, 0.f, 0.f, 0.f};
    acc[1] = (f32x4){0.f, 0.f, 0.f, 0.f};

    // named register staging sets (rule #20: no runtime-indexed reg arrays)
    f32x4 pa0, pa1, pa2, pa3;  short8 pz0, pz1, pz2, pz3;   // set P
    f32x4 qa0, qa1, qa2, qa3;  short8 qz0, qz1, qz2, qz3;   // set Q

    #define LOADT(A0, A1, A2, A3, Z0, Z1, Z2, Z3, k0)                        \
        do {                                                                 \
            const float* asrc = Ab + (size_t)(n0 + ar) * NN + (k0) + ac;     \
            A0 = *(const f32x4*)(asrc);                                      \
            A1 = *(const f32x4*)(asrc + 4);                                  \
            A2 = *(const f32x4*)(asrc + 8);                                  \
            A3 = *(const f32x4*)(asrc + 12);                                 \
            const unsigned short* zsrc = Zb + (size_t)(o0 + zo) * NN + (k0) + zc; \
            Z0 = *(const short8*)(zsrc);                                     \
            Z1 = *(const short8*)(zsrc + 8);                                 \
            Z2 = *(const short8*)(zsrc + 16);                                \
            Z3 = *(const short8*)(zsrc + 24);                                \
        } while (0)

    #define WRITET(buf, A0, A1, A2, A3, Z0, Z1, Z2, Z3)                      \
        do {                                                                 \
            *(short8*)&As[buf][ar][ac]     = cvt8(A0, A1);                   \
            *(short8*)&As[buf][ar][ac + 8] = cvt8(A2, A3);                   \
            *(short8*)&Zs[buf][zo][zc]      = Z0;                            \
            *(short8*)&Zs[buf][zo][zc + 8]  = Z1;                            \
            *(short8*)&Zs[buf][zo][zc + 16] = Z2;                            \
            *(short8*)&Zs[buf][zo][zc + 24] = Z3;                            \
        } while (0)

    #define MFMAS(cur)                                                       \
        do {                                                                 \
            _Pragma("unroll")                                                \
            for (int ks = 0; ks < 128; ks += 32) {                           \
                short8 af  = *(const short8*)&As[cur][wr + l15][ks + kgrp];  \
                short8 bf0 = *(const short8*)&Zs[cur][wc + l15][ks + kgrp];  \
                short8 bf1 = *(const short8*)&Zs[cur][wc + 16 + l15][ks + kgrp]; \
                acc[0] = __builtin_amdgcn_mfma_f32_16x16x32_bf16(af, bf0, acc[0], 0, 0, 0); \
                acc[1] = __builtin_amdgcn_mfma_f32_16x16x32_bf16(af, bf1, acc[1], 0, 0, 0); \
            }                                                                \
        } while (0)

    // prologue: tile0 -> buf0; tile1 -> set P
    LOADT(pa0, pa1, pa2, pa3, pz0, pz1, pz2, pz3, 0);
    WRITET(0, pa0, pa1, pa2, pa3, pz0, pz1, pz2, pz3);
    LOADT(pa0, pa1, pa2, pa3, pz0, pz1, pz2, pz3, 128);
    __syncthreads();

    // 16 K-steps (BK=128), unrolled x2 with named set roles
    for (int it = 0; it < 16; it += 2) {
        if (it + 2 < 16) LOADT(qa0, qa1, qa2, qa3, qz0, qz1, qz2, qz3, (it + 2) * 128);
        MFMAS(0);
        if (it + 1 < 16) WRITET(1, pa0, pa1, pa2, pa3, pz0, pz1, pz2, pz3);
        __syncthreads();
        if (it + 1 < 16) {
            if (it + 3 < 16) LOADT(pa0, pa1, pa2, pa3, pz0, pz1, pz2, pz3, (it + 3) * 128);
            MFMAS(1);
            if (it + 2 < 16) WRITET(0, qa0, qa1, qa2, qa3, qz0, qz1, qz2, qz3);
            __syncthreads();
        }
    }

    int drow = (lane >> 4) * 4;
    #pragma unroll
    for (int tt = 0; tt < 2; ++tt) {
        int o = o0 + wc + tt * 16 + l15;
        float bv = bias[o];
        #pragma unroll
        for (int r = 0; r < 4; ++r) {
            int n = n0 + wr + drow + r;
            float dv = dinv[b * NN + n];
            out[((size_t)b * NN + n) * FF + o] = dv * acc[tt][r] + bv;
        }
    }
    #undef LOADT
    #undef WRITET
    #undef MFMAS
}

extern "C" void kernel_launch(void* const* d_in, const int* in_sizes, int n_in,
                              void* d_out, int out_size, void* d_ws, size_t ws_size,
                              hipStream_t stream) {
    // Bind inputs by element count (all distinct; order-proof):
    const float *X = nullptr, *A = nullptr, *W = nullptr, *bias = nullptr;
    for (int i = 0; i < n_in; ++i) {
        switch (in_sizes[i]) {
            case 16777216: A    = (const float*)d_in[i]; break;  // [4,2048,2048]
            case 1048576:  X    = (const float*)d_in[i]; break;  // [4,2048,128]
            case 16384:    W    = (const float*)d_in[i]; break;  // [128,128]
            case 128:      bias = (const float*)d_in[i]; break;  // [128]
            default: break;
        }
    }
    float* out = (float*)d_out;
    if (!X || !A || !W || !bias) return;        // signature: absmax 0.7578125
    if (out_size != 4 * NN * FF) return;
    if (ws_size < (size_t)WS_NEED) return;

    float* dinv        = (float*)d_ws;                            // 32 KB
    unsigned short* Zt = (unsigned short*)((char*)d_ws + 32768);  // 2 MB bf16

    k1_deg<<<4 * NN, 256, 0, stream>>>(A, dinv);
    k2_zt<<<256, 256, 0, stream>>>(X, W, dinv, Zt);
    k3_mfma<<<512, 256, 0, stream>>>(A, Zt, dinv, bias, out);
}

// Round 15
// 56.369 us; speedup vs baseline: 1.0010x; 1.0010x over previous
//
#include <hip/hip_runtime.h>

// GraphConv: out = d ∘ (A @ ((d∘X) @ W^T)) + b,  d = rsqrt(clip(rowsum(A),1e-6))
// B=4, N=2048, F=128. All f32 I/O, size-based binding (R6-verified).
// R13 post-mortem: Abf16 staging rejected (k3 not fetch-bound). R14: k3
// restructured to tile 32n x 64o, BK=128 -> 16 iterations (was 32), 8 MFMA
// per wave per barrier (was 4), ~195 MB cache traffic (was 290). Depth-2
// register prefetch, named sets, double-buffered LDS. Same k-order =>
// absmax bit-identical (0.00390625). k1/k2 = R12 verbatim.

#define NN 2048
#define FF 128
#define WS_NEED (32768u + 4u * 128u * 2048u * 2u)   // dinv(32KB)+Zt(2MB)

typedef __attribute__((ext_vector_type(4))) float f32x4;
typedef __attribute__((ext_vector_type(8))) short short8;

// f32 -> bf16 round-to-nearest-even (finite inputs only)
__device__ inline unsigned short f2bf(float f) {
    unsigned u = __builtin_bit_cast(unsigned, f);
    u = (u + 0x7fffu + ((u >> 16) & 1u)) >> 16;
    return (unsigned short)u;
}

__device__ inline short8 cvt8(f32x4 a, f32x4 b) {
    short8 r;
    r[0] = (short)f2bf(a.x); r[1] = (short)f2bf(a.y);
    r[2] = (short)f2bf(a.z); r[3] = (short)f2bf(a.w);
    r[4] = (short)f2bf(b.x); r[5] = (short)f2bf(b.y);
    r[6] = (short)f2bf(b.z); r[7] = (short)f2bf(b.w);
    return r;
}

// ---- k1: dinv[row] = rsqrt(max(rowsum(A),1e-6))  [R12 verbatim] ------------
__global__ __launch_bounds__(256) void k1_deg(const float* __restrict__ A,
                                              float* __restrict__ dinv) {
    __shared__ float red[256];
    int row = blockIdx.x;
    int t = threadIdx.x;
    const f32x4* ap = (const f32x4*)(A + (size_t)row * NN);
    f32x4 v0 = ap[t];
    f32x4 v1 = ap[t + 256];
    red[t] = v0.x + v0.y + v0.z + v0.w + v1.x + v1.y + v1.z + v1.w;
    __syncthreads();
    #pragma unroll
    for (int s = 128; s > 0; s >>= 1) {
        if (t < s) red[t] += red[t + s];
        __syncthreads();
    }
    if (t == 0) dinv[row] = rsqrtf(fmaxf(red[0], 1e-6f));
}

// ---- k2: Zt[b][o][m] = bf16(dinv[b,m] * dot(X[b,m,:], W[o,:]))  [R12 verbatim]
__global__ __launch_bounds__(256) void k2_zt(const float* __restrict__ X,
                                             const float* __restrict__ W,
                                             const float* __restrict__ dinv,
                                             unsigned short* __restrict__ Zt) {
    __shared__ float Ws[FF * FF];           // 64 KB
    int blk = blockIdx.x;
    int b  = blk >> 6;                      // 0..3
    int mc = (blk >> 3) & 7;                // 0..7
    int oc = blk & 7;                       // 0..7
    int t  = threadIdx.x;
    int m  = mc * 256 + t;                  // 0..2047

    {
        f32x4* wd = (f32x4*)Ws;
        const f32x4* wsrc = (const f32x4*)W;
        #pragma unroll
        for (int j = 0; j < 16; ++j) wd[t + 256 * j] = wsrc[t + 256 * j];
    }
    __syncthreads();

    float acc[16];
    #pragma unroll
    for (int j = 0; j < 16; ++j) acc[j] = 0.f;

    const f32x4* xr = (const f32x4*)(X + ((size_t)b * NN + m) * FF);
    for (int f4 = 0; f4 < FF / 4; ++f4) {
        f32x4 xv = xr[f4];
        #pragma unroll
        for (int j = 0; j < 16; ++j) {
            f32x4 wv = *(const f32x4*)&Ws[(oc * 16 + j) * FF + f4 * 4];
            acc[j] += xv.x * wv.x + xv.y * wv.y + xv.z * wv.z + xv.w * wv.w;
        }
    }
    float dv = dinv[b * NN + m];
    #pragma unroll
    for (int j = 0; j < 16; ++j)
        Zt[((size_t)b * FF + oc * 16 + j) * NN + m] = f2bf(acc[j] * dv);
}

// ---- k3: out[b,n,o] = dinv[b,n] * sum_m A[b,n,m]*Z[m,o] + bias[o] ----------
// 512 blocks = b(4) x ntile(64: 32 rows) x ohalf(2: 64 cols). 4 waves in a
// 2x2 grid: wave w owns (16n x 32o) quadrant (wr=(w>>1)*16, wc=(w&1)*32).
// BK=128, 16 iterations; double-buffered LDS (51 KB); depth-2 register
// prefetch with named sets P/Q. Rows padded to 136 shorts (272 B -> 4-bank
// row step, 2-way aliasing = free). Fragment conventions identical to
// R10..R13 (verified). Same k-accumulation order => bit-identical output.
__global__ __launch_bounds__(256) void k3_mfma(const float* __restrict__ A,
                                               const unsigned short* __restrict__ Zt,
                                               const float* __restrict__ dinv,
                                               const float* __restrict__ bias,
                                               float* __restrict__ out) {
    __shared__ unsigned short As[2][32][136];   // A tile  [n][k] bf16 (17.4 KB)
    __shared__ unsigned short Zs[2][64][136];   // Z^T tile [o][k] bf16 (34.8 KB)
    int blk = blockIdx.x;                   // 0..511
    int b   = blk >> 7;                     // 0..3
    int rem = blk & 127;
    int n0  = (rem >> 1) * 32;              // 0..2016
    int o0  = (rem & 1) * 64;               // 0 or 64
    int t   = threadIdx.x;
    int w   = t >> 6, lane = t & 63;
    int wr  = (w >> 1) * 16;                // wave row offset
    int wc  = (w & 1) * 32;                 // wave col offset
    int l15 = lane & 15, kgrp = (lane >> 4) * 8;

    const float* Ab = A + (size_t)b * NN * NN;
    const unsigned short* Zb = Zt + (size_t)b * FF * NN;

    // staging assignments (BK=128 chunk)
    int ar = t >> 3;                        // 0..31 (A row)
    int ac = (t & 7) * 16;                  // 0..112 (A col, 16 bf16/thread)
    int zo = t >> 2;                        // 0..63 (Zt row)
    int zc = (t & 3) * 32;                  // 0..96 (Zt col, 32 bf16/thread)

    f32x4 acc[2];
    acc[0] = (f32x4){0.f, 0.f, 0.f, 0.f};
    acc[1] = (f32x4){0.f, 0.f, 0.f, 0.f};

    // named register staging sets (rule #20: no runtime-indexed reg arrays)
    f32x4 pa0, pa1, pa2, pa3;  short8 pz0, pz1, pz2, pz3;   // set P
    f32x4 qa0, qa1, qa2, qa3;  short8 qz0, qz1, qz2, qz3;   // set Q

    #define LOADT(A0, A1, A2, A3, Z0, Z1, Z2, Z3, k0)                        \
        do {                                                                 \
            const float* asrc = Ab + (size_t)(n0 + ar) * NN + (k0) + ac;     \
            A0 = *(const f32x4*)(asrc);                                      \
            A1 = *(const f32x4*)(asrc + 4);                                  \
            A2 = *(const f32x4*)(asrc + 8);                                  \
            A3 = *(const f32x4*)(asrc + 12);                                 \
            const unsigned short* zsrc = Zb + (size_t)(o0 + zo) * NN + (k0) + zc; \
            Z0 = *(const short8*)(zsrc);                                     \
            Z1 = *(const short8*)(zsrc + 8);                                 \
            Z2 = *(const short8*)(zsrc + 16);                                \
            Z3 = *(const short8*)(zsrc + 24);                                \
        } while (0)

    #define WRITET(buf, A0, A1, A2, A3, Z0, Z1, Z2, Z3)                      \
        do {                                                                 \
            *(short8*)&As[buf][ar][ac]     = cvt8(A0, A1);                   \
            *(short8*)&As[buf][ar][ac + 8] = cvt8(A2, A3);                   \
            *(short8*)&Zs[buf][zo][zc]      = Z0;                            \
            *(short8*)&Zs[buf][zo][zc + 8]  = Z1;                            \
            *(short8*)&Zs[buf][zo][zc + 16] = Z2;                            \
            *(short8*)&Zs[buf][zo][zc + 24] = Z3;                            \
        } while (0)

    #define MFMAS(cur)                                                       \
        do {                                                                 \
            _Pragma("unroll")                                                \
            for (int ks = 0; ks < 128; ks += 32) {                           \
                short8 af  = *(const short8*)&As[cur][wr + l15][ks + kgrp];  \
                short8 bf0 = *(const short8*)&Zs[cur][wc + l15][ks + kgrp];  \
                short8 bf1 = *(const short8*)&Zs[cur][wc + 16 + l15][ks + kgrp]; \
                acc[0] = __builtin_amdgcn_mfma_f32_16x16x32_bf16(af, bf0, acc[0], 0, 0, 0); \
                acc[1] = __builtin_amdgcn_mfma_f32_16x16x32_bf16(af, bf1, acc[1], 0, 0, 0); \
            }                                                                \
        } while (0)

    // prologue: tile0 -> buf0; tile1 -> set P
    LOADT(pa0, pa1, pa2, pa3, pz0, pz1, pz2, pz3, 0);
    WRITET(0, pa0, pa1, pa2, pa3, pz0, pz1, pz2, pz3);
    LOADT(pa0, pa1, pa2, pa3, pz0, pz1, pz2, pz3, 128);
    __syncthreads();

    // 16 K-steps (BK=128), unrolled x2 with named set roles
    for (int it = 0; it < 16; it += 2) {
        if (it + 2 < 16) LOADT(qa0, qa1, qa2, qa3, qz0, qz1, qz2, qz3, (it + 2) * 128);
        MFMAS(0);
        if (it + 1 < 16) WRITET(1, pa0, pa1, pa2, pa3, pz0, pz1, pz2, pz3);
        __syncthreads();
        if (it + 1 < 16) {
            if (it + 3 < 16) LOADT(pa0, pa1, pa2, pa3, pz0, pz1, pz2, pz3, (it + 3) * 128);
            MFMAS(1);
            if (it + 2 < 16) WRITET(0, qa0, qa1, qa2, qa3, qz0, qz1, qz2, qz3);
            __syncthreads();
        }
    }

    int drow = (lane >> 4) * 4;
    #pragma unroll
    for (int tt = 0; tt < 2; ++tt) {
        int o = o0 + wc + tt * 16 + l15;
        float bv = bias[o];
        #pragma unroll
        for (int r = 0; r < 4; ++r) {
            int n = n0 + wr + drow + r;
            float dv = dinv[b * NN + n];
            out[((size_t)b * NN + n) * FF + o] = dv * acc[tt][r] + bv;
        }
    }
    #undef LOADT
    #undef WRITET
    #undef MFMAS
}

extern "C" void kernel_launch(void* const* d_in, const int* in_sizes, int n_in,
                              void* d_out, int out_size, void* d_ws, size_t ws_size,
                              hipStream_t stream) {
    // Bind inputs by element count (all distinct; order-proof):
    const float *X = nullptr, *A = nullptr, *W = nullptr, *bias = nullptr;
    for (int i = 0; i < n_in; ++i) {
        switch (in_sizes[i]) {
            case 16777216: A    = (const float*)d_in[i]; break;  // [4,2048,2048]
            case 1048576:  X    = (const float*)d_in[i]; break;  // [4,2048,128]
            case 16384:    W    = (const float*)d_in[i]; break;  // [128,128]
            case 128:      bias = (const float*)d_in[i]; break;  // [128]
            default: break;
        }
    }
    float* out = (float*)d_out;
    if (!X || !A || !W || !bias) return;        // signature: absmax 0.7578125
    if (out_size != 4 * NN * FF) return;
    if (ws_size < (size_t)WS_NEED) return;

    float* dinv        = (float*)d_ws;                            // 32 KB
    unsigned short* Zt = (unsigned short*)((char*)d_ws + 32768);  // 2 MB bf16

    k1_deg<<<4 * NN, 256, 0, stream>>>(A, dinv);
    k2_zt<<<256, 256, 0, stream>>>(X, W, dinv, Zt);
    k3_mfma<<<512, 256, 0, stream>>>(A, Zt, dinv, bias, out);
}